// Round 7
// baseline (1562.008 us; speedup 1.0000x reference)
//
#include <hip/hip_runtime.h>
#include <hip/hip_bf16.h>

typedef __hip_bfloat16 bf16;
typedef __attribute__((ext_vector_type(8))) short bf16x8;
typedef __attribute__((ext_vector_type(16))) float f32x16;

#define EPI_BF16 1
#define EPI_BF16_T 2
#define EPI_F32_RES 3
#define EPI_BF16_GELU 4
#define EPI_BF16_MUL 5
#define EPI_F32_KSPLIT 6

__device__ __forceinline__ void gload_lds16(const bf16* g, char* l) {
  __builtin_amdgcn_global_load_lds(
      (const __attribute__((address_space(1))) unsigned int*)g,
      (__attribute__((address_space(3))) unsigned int*)l, 16, 0, 0);
}

__device__ __forceinline__ unsigned lds_addr(const void* p) {
  return (unsigned)(size_t)(const __attribute__((address_space(3))) char*)p;
}

template<int IMM>
__device__ __forceinline__ bf16x8 dsr(unsigned addr) {
  bf16x8 d;
  asm volatile("ds_read_b128 %0, %1 offset:%c2" : "=v"(d) : "v"(addr), "i"(IMM));
  return d;
}

#define SCHED0() __builtin_amdgcn_sched_barrier(0)
#define VMG(N)                                       \
  do {                                               \
    SCHED0();                                        \
    asm volatile("s_waitcnt vmcnt(" #N ")");         \
    SCHED0();                                        \
  } while (0)
#define BAR_LGKM()                                   \
  do {                                               \
    __builtin_amdgcn_s_barrier();                    \
    SCHED0();                                        \
    asm volatile("s_waitcnt lgkmcnt(0)");            \
    SCHED0();                                        \
  } while (0)

#define MM(a, b, c) __builtin_amdgcn_mfma_f32_32x32x16_bf16(a, b, c, 0, 0, 0)

// one phase's reads: full BK=32 sub-buffer, 8 A-frags (4 mi x 2 ks) + 4 B-frags
#define RD12(SB)                                                            \
  do {                                                                      \
    aF00 = dsr<(SB) + 0>(aK0);    aF10 = dsr<(SB) + 2048>(aK0);             \
    aF20 = dsr<(SB) + 4096>(aK0); aF30 = dsr<(SB) + 6144>(aK0);             \
    bF00 = dsr<(SB) + 0>(bK0);    bF10 = dsr<(SB) + 2048>(bK0);             \
    aF01 = dsr<(SB) + 0>(aK1);    aF11 = dsr<(SB) + 2048>(aK1);             \
    aF21 = dsr<(SB) + 4096>(aK1); aF31 = dsr<(SB) + 6144>(aK1);             \
    bF01 = dsr<(SB) + 0>(bK1);    bF11 = dsr<(SB) + 2048>(bK1);             \
  } while (0)

// 16 MFMAs = 8 C-frags x 2 k-steps (8 independent chains of 2), setprio (T5)
#define MF16()                                                              \
  do {                                                                      \
    __builtin_amdgcn_s_setprio(1);                                          \
    c00 = MM(aF00, bF00, c00); c01 = MM(aF00, bF10, c01);                   \
    c10 = MM(aF10, bF00, c10); c11 = MM(aF10, bF10, c11);                   \
    c20 = MM(aF20, bF00, c20); c21 = MM(aF20, bF10, c21);                   \
    c30 = MM(aF30, bF00, c30); c31 = MM(aF30, bF10, c31);                   \
    c00 = MM(aF01, bF01, c00); c01 = MM(aF01, bF11, c01);                   \
    c10 = MM(aF11, bF01, c10); c11 = MM(aF11, bF11, c11);                   \
    c20 = MM(aF21, bF01, c20); c21 = MM(aF21, bF11, c21);                   \
    c30 = MM(aF31, bF01, c30); c31 = MM(aF31, bF11, c31);                   \
    __builtin_amdgcn_s_setprio(0);                                          \
  } while (0)

// C = A(MxK,row-major,lda) * B^T, B stored [N x K] row-major (ldb).
// 256x256 tile, BK=64 as two K=32 sub-buffers, 8 waves (2M x 4N),
// per-wave 128x64 output = 4x2 frags of 32x32x16 MFMA (2 k-steps/sub-buffer).
// LDS 128KB = 4 sub-buffers x (A 16KB @ idx*16K, B 16KB @ +64K), idx=(tile&1)*2|kh.
// XOR swizzle: chunk(16B) ^= (row>>1)&3; staged via pre-swizzled global source.
// 4 phases / 2 K-tiles. Phase: {12 ds_reads | stage 1 unit (4 gloads) | barrier |
// lgkm0 | 16 MFMA | vmcnt guard | barrier}. Units staged 3 phases before read;
// guard vmcnt(8)=2 younger units before the trailing barrier of the phase
// preceding the read (per-wave vmcnt + barrier join => chip-wide). vmcnt
// reaches 0 only in the final iteration (T4).
template<int EPI>
__global__ __launch_bounds__(512, 2) void gemm256_k(
    const bf16* __restrict__ A, const bf16* __restrict__ B,
    void* __restrict__ Cv, const void* __restrict__ auxv,
    int N, int K, int lda, int ldb,
    long sAz, long sBz, long sCz, int batchM)
{
  __shared__ bf16 lds[65536];  // 128KB

  // T1: XCD-aware swizzle over the flattened grid (all grids are %8==0)
  const int gx = gridDim.x, gy = gridDim.y;
  int lid = (blockIdx.z * gy + blockIdx.y) * gx + blockIdx.x;
  const int cpx = (gx * gy * gridDim.z) >> 3;
  lid = (lid & 7) * cpx + (lid >> 3);
  const int bx = lid % gx;
  const int rem = lid / gx;
  const int by = rem % gy;
  const int z = rem / gy;

  int zb = z, part = 0;
  if constexpr (EPI == EPI_F32_KSPLIT) { zb = z & 1; part = z >> 1; }
  A += (size_t)zb * (size_t)sAz + (size_t)part * (size_t)batchM;
  B += (size_t)zb * (size_t)sBz + (size_t)part * (size_t)batchM;

  const int brow = by * 256, bcol = bx * 256;
  const int t = threadIdx.x;
  const int w = t >> 6, lane = t & 63;
  const int wrow = (w >> 2) * 128;  // 2 M-waves
  const int wcol = (w & 3) * 64;    // 4 N-waves
  const int l31 = lane & 31, lhi = lane >> 5;

  f32x16 z16;
#pragma unroll
  for (int i = 0; i < 16; ++i) z16[i] = 0.f;
  f32x16 c00 = z16, c01 = z16, c10 = z16, c11 = z16,
         c20 = z16, c21 = z16, c30 = z16, c31 = z16;

  // ---- hoisted per-thread staging pointers (pre-swizzled source, rule #21) ----
  // slot s = (j*8+w)*64 + lane; row = s>>2; chunk = s&3; global k-chunk
  // cs = (s&3) ^ ((s>>3)&3) = (lane&3) ^ ((lane>>3)&3) (bases are %8==0).
  const int csS = (lane & 3) ^ ((lane >> 3) & 3);
  const int rS0 = w * 16 + (lane >> 2);
  const int rS1 = (8 + w) * 16 + (lane >> 2);
  const bf16* pA0 = A + (size_t)(brow + rS0) * lda + csS * 8;
  const bf16* pA1 = A + (size_t)(brow + rS1) * lda + csS * 8;
  const bf16* pB0 = B + (size_t)(bcol + rS0) * ldb + csS * 8;
  const bf16* pB1 = B + (size_t)(bcol + rS1) * ldb + csS * 8;
  const unsigned ldsOf0 = (unsigned)(w * 64 * 16);
  const unsigned ldsOf1 = (unsigned)((8 + w) * 64 * 16);

  auto STAGE1 = [&](int tile, int kh) {  // one unit = 4 gloads/thread
    const int idx = ((tile & 1) << 1) | kh;
    char* base = (char*)lds + (idx << 14);
    const int kk = tile * 64 + kh * 32;
    gload_lds16(pA0 + kk, base + ldsOf0);
    gload_lds16(pB0 + kk, base + 65536 + ldsOf0);
    gload_lds16(pA1 + kk, base + ldsOf1);
    gload_lds16(pB1 + kk, base + 65536 + ldsOf1);
  };

  // ---- per-thread LDS read addresses (32x32x16 frags) ----
  // A: row = wrow + mi*32 + l31 (mi*32 -> +2048B imm), k-chunk = (ks*2+lhi) ^ ((row>>1)&3)
  // (row>>1)&3 == (lane>>1)&3; ks=1 flips chunk bit1 -> addr XOR 32.
  const unsigned sw = (unsigned)((lhi ^ ((lane >> 1) & 3)) * 16);
  const unsigned aK0 = lds_addr(lds) + (unsigned)((wrow + l31) * 64) + sw;
  const unsigned aK1 = aK0 ^ 32u;
  const unsigned bK0 = lds_addr(lds) + 65536u + (unsigned)((wcol + l31) * 64) + sw;
  const unsigned bK1 = bK0 ^ 32u;

  // prologue: stage units for ph1..ph3; ph4's unit staged at ph1
  STAGE1(0, 0);
  STAGE1(0, 1);
  STAGE1(1, 0);
  VMG(8);
  __builtin_amdgcn_s_barrier();

  const int NT = K >> 6;  // even, >= 4 for all our shapes
  bf16x8 aF00, aF10, aF20, aF30, aF01, aF11, aF21, aF31;
  bf16x8 bF00, bF10, bF01, bF11;

  for (int t2 = 0; t2 < NT; t2 += 2) {
    const bool s3 = (t2 + 2) < NT;
    const bool s7 = (t2 + 3) < NT;

    // ph1: (t2,k0) [SB0]; stage (t2+1,k1)->SB3 (read ph4; SB3 last read prev ph4)
    RD12(0);
    STAGE1(t2 + 1, 1);
    BAR_LGKM();
    MF16();
    VMG(8);                        // guard ph2's (t2,k1) [prev ph3 / prologue]
    __builtin_amdgcn_s_barrier();

    // ph2: (t2,k1) [SB1=16384]; stage (t2+2,k0)->SB0
    RD12(16384);
    if (s3) STAGE1(t2 + 2, 0);
    BAR_LGKM();
    MF16();
    if (s3) VMG(8); else VMG(4);   // guard ph3's (t2+1,k0) [prev ph4 / prologue]
    __builtin_amdgcn_s_barrier();

    // ph3: (t2+1,k0) [SB2=32768]; stage (t2+2,k1)->SB1
    RD12(32768);
    if (s3) STAGE1(t2 + 2, 1);
    BAR_LGKM();
    MF16();
    if (s3) VMG(8); else VMG(0);   // guard ph4's (t2+1,k1) [cur ph1]
    __builtin_amdgcn_s_barrier();

    // ph4: (t2+1,k1) [SB3=49152]; stage (t2+3,k0)->SB2
    RD12(49152);
    if (s7) STAGE1(t2 + 3, 0);
    BAR_LGKM();
    MF16();
    if (s3) { if (s7) VMG(8); else VMG(4); }  // guard next ph1's (t2+2,k0) [cur ph2]
    __builtin_amdgcn_s_barrier();
  }

  // ---- Epilogue. 32x32 C/D frag: col = lane&31,
  // row = (reg&3) + 8*(reg>>2) + 4*(lane>>5)  [m74/m101-verified] ----
  f32x16 acc[4][2] = {{c00, c01}, {c10, c11}, {c20, c21}, {c30, c31}};
  if constexpr (EPI == EPI_BF16_T) {
    bf16* C = (bf16*)Cv + (size_t)zb * (size_t)sCz;
#pragma unroll
    for (int mi = 0; mi < 4; ++mi) {
#pragma unroll
      for (int q = 0; q < 4; ++q) {
        const int mbase = brow + wrow + mi * 32 + q * 8 + lhi * 4;
        const int bi = mbase / batchM;
        const int ms = mbase - bi * batchM;
        const size_t base = (size_t)bi * (size_t)N * (size_t)batchM + (size_t)ms;
#pragma unroll
        for (int ni = 0; ni < 2; ++ni) {
          const int n = bcol + wcol + ni * 32 + l31;
          union { short4 s; short h4[4]; } u;
#pragma unroll
          for (int r2 = 0; r2 < 4; ++r2) {
            bf16 bv = __float2bfloat16(acc[mi][ni][q * 4 + r2]);
            u.h4[r2] = *(short*)&bv;
          }
          *(short4*)(C + base + (size_t)n * (size_t)batchM) = u.s;
        }
      }
    }
  } else {
#pragma unroll
    for (int mi = 0; mi < 4; ++mi) {
#pragma unroll
      for (int q = 0; q < 4; ++q) {
#pragma unroll
        for (int r2 = 0; r2 < 4; ++r2) {
          const int m = brow + wrow + mi * 32 + q * 8 + lhi * 4 + r2;
#pragma unroll
          for (int ni = 0; ni < 2; ++ni) {
            const int n = bcol + wcol + ni * 32 + l31;
            const size_t idx = (size_t)m * (size_t)N + (size_t)n;
            float v = acc[mi][ni][q * 4 + r2];
            if constexpr (EPI == EPI_F32_KSPLIT) {
              float* C = (part ? (float*)auxv : (float*)Cv) + (size_t)zb * (size_t)sCz;
              C[idx] = v;
            } else if constexpr (EPI == EPI_F32_RES) {
              ((float*)Cv)[idx] = v + ((const float*)auxv)[idx];
            } else if constexpr (EPI == EPI_BF16) {
              ((bf16*)Cv)[idx] = __float2bfloat16(v);
            } else if constexpr (EPI == EPI_BF16_GELU) {
              v = 0.5f * v * (1.0f + erff(v * 0.70710678118654752f));
              ((bf16*)Cv)[idx] = __float2bfloat16(v);
            } else if constexpr (EPI == EPI_BF16_MUL) {
              v = v * __bfloat162float(((const bf16*)auxv)[idx]);
              ((bf16*)Cv)[idx] = __float2bfloat16(v);
            }
          }
        }
      }
    }
  }
}

// LayerNorm over rows of 2048 fp32 -> bf16 (biased var, eps=1e-5, weight, no bias)
__global__ __launch_bounds__(256) void ln_k(const float* __restrict__ x,
                                            const float* __restrict__ w,
                                            bf16* __restrict__ out) {
  const int row = blockIdx.x;
  const int t = threadIdx.x;
  const float* xr = x + (size_t)row * 2048;
  float4 a = ((const float4*)xr)[2 * t];
  float4 b = ((const float4*)xr)[2 * t + 1];
  float s = a.x + a.y + a.z + a.w + b.x + b.y + b.z + b.w;
  float ss = a.x * a.x + a.y * a.y + a.z * a.z + a.w * a.w +
             b.x * b.x + b.y * b.y + b.z * b.z + b.w * b.w;
#pragma unroll
  for (int o = 1; o < 64; o <<= 1) { s += __shfl_xor(s, o); ss += __shfl_xor(ss, o); }
  __shared__ float ps[4], pss[4];
  if ((t & 63) == 0) { ps[t >> 6] = s; pss[t >> 6] = ss; }
  __syncthreads();
  s = ps[0] + ps[1] + ps[2] + ps[3];
  ss = pss[0] + pss[1] + pss[2] + pss[3];
  const float mean = s * (1.0f / 2048.0f);
  const float var = ss * (1.0f / 2048.0f) - mean * mean;
  const float rstd = rsqrtf(var + 1e-5f);
  float4 wa = ((const float4*)w)[2 * t];
  float4 wb = ((const float4*)w)[2 * t + 1];
  bf16* o8 = out + (size_t)row * 2048 + (size_t)t * 8;
  o8[0] = __float2bfloat16((a.x - mean) * rstd * wa.x);
  o8[1] = __float2bfloat16((a.y - mean) * rstd * wa.y);
  o8[2] = __float2bfloat16((a.z - mean) * rstd * wa.z);
  o8[3] = __float2bfloat16((a.w - mean) * rstd * wa.w);
  o8[4] = __float2bfloat16((b.x - mean) * rstd * wb.x);
  o8[5] = __float2bfloat16((b.y - mean) * rstd * wb.y);
  o8[6] = __float2bfloat16((b.z - mean) * rstd * wb.z);
  o8[7] = __float2bfloat16((b.w - mean) * rstd * wb.w);
}

// softmax over rows of 2048: input = sp0 + sp1 (split-K partials), scale 1/8 -> bf16
__global__ __launch_bounds__(256) void softmax2_k(const float* __restrict__ s0,
                                                  const float* __restrict__ s1,
                                                  bf16* __restrict__ o) {
  const int row = blockIdx.x;
  const int t = threadIdx.x;
  const float* r0 = s0 + (size_t)row * 2048;
  const float* r1 = s1 + (size_t)row * 2048;
  float4 a = ((const float4*)r0)[2 * t];
  float4 b = ((const float4*)r0)[2 * t + 1];
  float4 c = ((const float4*)r1)[2 * t];
  float4 d = ((const float4*)r1)[2 * t + 1];
  float v[8] = {a.x + c.x, a.y + c.y, a.z + c.z, a.w + c.w,
                b.x + d.x, b.y + d.y, b.z + d.z, b.w + d.w};
  float m = -1e30f;
#pragma unroll
  for (int i = 0; i < 8; ++i) { v[i] *= 0.125f; m = fmaxf(m, v[i]); }
#pragma unroll
  for (int o2 = 1; o2 < 64; o2 <<= 1) m = fmaxf(m, __shfl_xor(m, o2));
  __shared__ float red[4];
  if ((t & 63) == 0) red[t >> 6] = m;
  __syncthreads();
  m = fmaxf(fmaxf(red[0], red[1]), fmaxf(red[2], red[3]));
  float sum = 0.f;
#pragma unroll
  for (int i = 0; i < 8; ++i) { v[i] = __expf(v[i] - m); sum += v[i]; }
#pragma unroll
  for (int o2 = 1; o2 < 64; o2 <<= 1) sum += __shfl_xor(sum, o2);
  __syncthreads();
  if ((t & 63) == 0) red[t >> 6] = sum;
  __syncthreads();
  sum = red[0] + red[1] + red[2] + red[3];
  const float inv = 1.0f / sum;
  bf16* po = o + (size_t)row * 2048 + (size_t)t * 8;
#pragma unroll
  for (int i = 0; i < 8; ++i) po[i] = __float2bfloat16(v[i] * inv);
}

// fp32 [K][N] -> bf16 [N][K]  (LDS-tiled transpose + downconvert)
__global__ __launch_bounds__(256) void transp_k(const float* __restrict__ in,
                                                bf16* __restrict__ out,
                                                int K, int N) {
  __shared__ float tile[32][33];
  const int bn = blockIdx.x * 32;
  const int bk = blockIdx.y * 32;
  const int tx = threadIdx.x;
  const int ty = threadIdx.y;
#pragma unroll
  for (int i = 0; i < 32; i += 8)
    tile[ty + i][tx] = in[(size_t)(bk + ty + i) * N + bn + tx];
  __syncthreads();
#pragma unroll
  for (int i = 0; i < 32; i += 8)
    out[(size_t)(bn + ty + i) * K + bk + tx] = __float2bfloat16(tile[tx][ty + i]);
}

extern "C" void kernel_launch(void* const* d_in, const int* in_sizes, int n_in,
                              void* d_out, int out_size, void* d_ws, size_t ws_size,
                              hipStream_t stream) {
  (void)in_sizes; (void)n_in; (void)out_size; (void)ws_size;
  const float* x   = (const float*)d_in[0];
  const float* lnw = (const float*)d_in[1];
  const float* w_q = (const float*)d_in[2];
  const float* w_k = (const float*)d_in[3];
  const float* w_v = (const float*)d_in[4];
  const float* w_o = (const float*)d_in[5];
  const float* w_g = (const float*)d_in[6];
  const float* w_u = (const float*)d_in[7];
  const float* w_d = (const float*)d_in[8];
  float* out = (float*)d_out;

  const int E = 2048, F = 8192;
  const size_t MB = 1024ull * 1024ull;
  char* ws = (char*)d_ws;

  // ---- workspace (288 MB, regions reused across phases) ----
  bf16* wq_t = (bf16*)(ws + 0 * MB);     // 8MB  [E][E] = w_q^T
  bf16* wk_t = (bf16*)(ws + 8 * MB);     // 8MB
  bf16* wv_t = (bf16*)(ws + 16 * MB);    // 8MB
  bf16* wo_t = (bf16*)(ws + 24 * MB);    // 8MB
  bf16* wg_t = (bf16*)(ws + 32 * MB);    // 32MB [F][E] = w_gate^T
  bf16* wu_t = (bf16*)(ws + 64 * MB);    // 32MB
  bf16* wd_t = (bf16*)(ws + 96 * MB);    // 32MB [E][F] = w_down^T
  bf16*  h   = (bf16*)(ws + 128 * MB);   // 32MB  h -> sp0 -> h2
  float* sp0 = (float*)(ws + 128 * MB);
  bf16*  h2  = (bf16*)(ws + 128 * MB);
  bf16*  qt    = (bf16*)(ws + 160 * MB); // 32MB  qt -> attnT -> gc(lo)
  bf16*  attnT = (bf16*)(ws + 160 * MB);
  bf16*  gc    = (bf16*)(ws + 160 * MB); // 64MB [160,224)
  bf16*  kt  = (bf16*)(ws + 192 * MB);   // 32MB  kt -> wts -> gc(hi)
  bf16*  wts = (bf16*)(ws + 192 * MB);
  bf16*  vm  = (bf16*)(ws + 224 * MB);   // 32MB  vm -> x2(lo)
  float* x2  = (float*)(ws + 224 * MB);  // 64MB [224,288)
  float* sp1 = (float*)(ws + 256 * MB);  // 32MB  (dead before x2 grows over it)

  dim3 blk(256), tb(32, 8), g512(512);

  transp_k<<<dim3(E / 32, E / 32), tb, 0, stream>>>(w_q, wq_t, E, E);
  transp_k<<<dim3(E / 32, E / 32), tb, 0, stream>>>(w_k, wk_t, E, E);
  transp_k<<<dim3(E / 32, E / 32), tb, 0, stream>>>(w_v, wv_t, E, E);
  transp_k<<<dim3(E / 32, E / 32), tb, 0, stream>>>(w_o, wo_t, E, E);
  transp_k<<<dim3(F / 32, E / 32), tb, 0, stream>>>(w_g, wg_t, E, F);
  transp_k<<<dim3(F / 32, E / 32), tb, 0, stream>>>(w_u, wu_t, E, F);
  transp_k<<<dim3(E / 32, F / 32), tb, 0, stream>>>(w_d, wd_t, F, E);

  ln_k<<<8192, blk, 0, stream>>>(x, lnw, h);

  // q,k written transposed per batch: qt[b][e][s]; v natural: vm[b*s][e']
  gemm256_k<EPI_BF16_T><<<dim3(8, 32, 1), g512, 0, stream>>>(h, wq_t, qt, nullptr,
      2048, 2048, 2048, 2048, 0, 0, 0, 4096);
  gemm256_k<EPI_BF16_T><<<dim3(8, 32, 1), g512, 0, stream>>>(h, wk_t, kt, nullptr,
      2048, 2048, 2048, 2048, 0, 0, 0, 4096);
  gemm256_k<EPI_BF16><<<dim3(8, 32, 1), g512, 0, stream>>>(h, wv_t, vm, nullptr,
      2048, 2048, 2048, 2048, 0, 0, 0, 1);

  // scores split-K: z = (part<<1)|batch; partial p sums s in [p*2048,(p+1)*2048)
  gemm256_k<EPI_F32_KSPLIT><<<dim3(8, 8, 4), g512, 0, stream>>>(qt, kt, sp0, sp1,
      2048, 2048, 4096, 4096, (long)2048 * 4096, (long)2048 * 4096,
      (long)2048 * 2048, 2048);

  softmax2_k<<<4096, blk, 0, stream>>>(sp0, sp1, wts);

  // attn[b][e][s] = wts[b] @ vm[b]^T -> stored transposed: attnT[b][s][e]
  gemm256_k<EPI_BF16_T><<<dim3(16, 8, 2), g512, 0, stream>>>(wts, vm, attnT, nullptr,
      4096, 2048, 2048, 2048, (long)2048 * 2048, (long)4096 * 2048,
      (long)4096 * 2048, 2048);

  // x2 = attnT @ w_o + x   (fp32)
  gemm256_k<EPI_F32_RES><<<dim3(8, 32, 1), g512, 0, stream>>>(attnT, wo_t, x2, x,
      2048, 2048, 2048, 2048, 0, 0, 0, 1);

  ln_k<<<8192, blk, 0, stream>>>(x2, lnw, h2);

  // FFN in 2 chunks of F/2=4096: gate->gelu, up*gate, down(+residual/accumulate)
  for (int c = 0; c < 2; ++c) {
    gemm256_k<EPI_BF16_GELU><<<dim3(16, 32, 1), g512, 0, stream>>>(
        h2, wg_t + (size_t)c * 4096 * 2048, gc, nullptr,
        4096, 2048, 2048, 2048, 0, 0, 0, 1);
    gemm256_k<EPI_BF16_MUL><<<dim3(16, 32, 1), g512, 0, stream>>>(
        h2, wu_t + (size_t)c * 4096 * 2048, gc, gc,
        4096, 2048, 2048, 2048, 0, 0, 0, 1);
    gemm256_k<EPI_F32_RES><<<dim3(8, 32, 1), g512, 0, stream>>>(
        gc, wd_t + (size_t)c * 4096, out,
        (c == 0 ? (const void*)x2 : (const void*)out),
        2048, 4096, 4096, 8192, 0, 0, 0, 1);
  }
}

// Round 8
// 1480.194 us; speedup vs baseline: 1.0553x; 1.0553x over previous
//
#include <hip/hip_runtime.h>
#include <hip/hip_bf16.h>

typedef __hip_bfloat16 bf16;
typedef __attribute__((ext_vector_type(8))) short bf16x8;
typedef __attribute__((ext_vector_type(4))) float f32x4;

#define EPI_BF16 1
#define EPI_BF16_T 2
#define EPI_F32_RES 3
#define EPI_BF16_GELU 4
#define EPI_BF16_MUL 5
#define EPI_F32_KSPLIT 6

__device__ __forceinline__ void gload_lds16(const bf16* g, char* l) {
  __builtin_amdgcn_global_load_lds(
      (const __attribute__((address_space(1))) unsigned int*)g,
      (__attribute__((address_space(3))) unsigned int*)l, 16, 0, 0);
}

__device__ __forceinline__ unsigned lds_addr(const void* p) {
  return (unsigned)(size_t)(const __attribute__((address_space(3))) char*)p;
}

template<int IMM>
__device__ __forceinline__ bf16x8 dsr(unsigned addr) {
  bf16x8 d;
  asm volatile("ds_read_b128 %0, %1 offset:%c2" : "=v"(d) : "v"(addr), "i"(IMM));
  return d;
}

#define SCHED0() __builtin_amdgcn_sched_barrier(0)
#define VMG(N)                                       \
  do {                                               \
    SCHED0();                                        \
    asm volatile("s_waitcnt vmcnt(" #N ")");         \
    SCHED0();                                        \
  } while (0)
#define BAR_LGKM()                                   \
  do {                                               \
    __builtin_amdgcn_s_barrier();                    \
    SCHED0();                                        \
    asm volatile("s_waitcnt lgkmcnt(0)");            \
    SCHED0();                                        \
  } while (0)

// phase reads: X = A mi0-3 + B nj0-3 (8 x b128), Y = A mi4-7 (4 x b128).
// BUF = sub-buffer byte offset ((par<<1)|kh)*16384, compile-time.
#define RDX(BUF)                                                            \
  do {                                                                      \
    aR[0] = dsr<(BUF) + 0>(aAddr);    aR[1] = dsr<(BUF) + 1024>(aAddr);     \
    aR[2] = dsr<(BUF) + 2048>(aAddr); aR[3] = dsr<(BUF) + 3072>(aAddr);     \
    bR[0] = dsr<(BUF) + 0>(bAddr);    bR[1] = dsr<(BUF) + 1024>(bAddr);     \
    bR[2] = dsr<(BUF) + 2048>(bAddr); bR[3] = dsr<(BUF) + 3072>(bAddr);     \
  } while (0)
#define RDY(BUF)                                                            \
  do {                                                                      \
    aR[0] = dsr<(BUF) + 4096>(aAddr); aR[1] = dsr<(BUF) + 5120>(aAddr);     \
    aR[2] = dsr<(BUF) + 6144>(aAddr); aR[3] = dsr<(BUF) + 7168>(aAddr);     \
  } while (0)

// 16 independent MFMAs (distinct accs; one K=32 half per phase), setprio (T5).
#define MFQH(MB)                                                            \
  do {                                                                      \
    __builtin_amdgcn_s_setprio(1);                                          \
    _Pragma("unroll") for (int mi_ = 0; mi_ < 4; ++mi_)                     \
        _Pragma("unroll") for (int nj_ = 0; nj_ < 4; ++nj_)                 \
            acc[(MB) * 4 + mi_][nj_] =                                      \
                __builtin_amdgcn_mfma_f32_16x16x32_bf16(                    \
                    aR[mi_], bR[nj_], acc[(MB) * 4 + mi_][nj_], 0, 0, 0);   \
    __builtin_amdgcn_s_setprio(0);                                          \
  } while (0)

// C = A(MxK,row-major,lda) * B^T, B stored [N x K] row-major (ldb).
// 256x256 tile, BK=64 split in two K-halves, 8 waves (2M x 4N),
// per-wave 128x64 = 8x4 frags of 16x16x32 MFMA.
// LDS 128KB as 4 sub-buffers per operand: (par=tile&1, kh) 16KB each.
// 8 phases / 2 K-tiles; counted-vmcnt pipeline (see R5/R6 derivation).
template<int EPI>
__global__ __launch_bounds__(512, 2) void gemm256_k(
    const bf16* __restrict__ A, const bf16* __restrict__ B,
    void* __restrict__ Cv, const void* __restrict__ auxv,
    int N, int K, int lda, int ldb,
    long sAz, long sBz, long sCz, int batchM)
{
  __shared__ bf16 lds[65536];  // 128KB: A units [0,64K), B units [64K,128K)

  // T1: XCD-aware swizzle over the flattened grid (all grids are %8==0)
  const int gx = gridDim.x, gy = gridDim.y;
  int lid = (blockIdx.z * gy + blockIdx.y) * gx + blockIdx.x;
  const int cpx = (gx * gy * gridDim.z) >> 3;
  lid = (lid & 7) * cpx + (lid >> 3);
  const int bx = lid % gx;
  const int rem = lid / gx;
  const int by = rem % gy;
  const int z = rem / gy;

  int zb = z, part = 0;
  if constexpr (EPI == EPI_F32_KSPLIT) { zb = z & 1; part = z >> 1; }
  A += (size_t)zb * (size_t)sAz + (size_t)part * (size_t)batchM;
  B += (size_t)zb * (size_t)sBz + (size_t)part * (size_t)batchM;

  const int brow = by * 256, bcol = bx * 256;
  const int t = threadIdx.x;
  const int w = t >> 6, lane = t & 63;
  const int wrow = (w >> 2) * 128;  // 2 M-waves
  const int wcol = (w & 3) * 64;    // 4 N-waves
  const int l15 = lane & 15, lg = lane >> 4;

  f32x4 acc[8][4];
#pragma unroll
  for (int i = 0; i < 8; ++i)
#pragma unroll
    for (int j = 0; j < 4; ++j) {
      f32x4 zz = {0.f, 0.f, 0.f, 0.f};
      acc[i][j] = zz;
    }

  // Stage one (tile,kh) unit: A 256x32 (16KB) + B 256x32, 4 gloads/thread.
  // Sub-buffer rows: 32 bf16 = 4 chunks of 16B; chunk ^= (row>>1)&3; global
  // source pre-swizzled with the same involution (rule #21).
  auto STAGE1 = [&](int tile, int kh) {
    const int par = tile & 1;
    char* Ad = (char*)lds + (((par << 1) | kh) << 14);
    char* Bd = Ad + 65536;
    const int kk = tile * 64 + kh * 32;
    const int csw = (lane >> 3) & 3;
#pragma unroll
    for (int j = 0; j < 2; ++j) {
      const int bslot = (j * 8 + w) * 64;   // wave-uniform 16B-slot base
      const int slot = bslot + lane;
      const int r = slot >> 2;
      const int cs = (slot & 3) ^ csw;
      gload_lds16(A + (size_t)(brow + r) * lda + kk + cs * 8, Ad + bslot * 16);
      gload_lds16(B + (size_t)(bcol + r) * ldb + kk + cs * 8, Bd + bslot * 16);
    }
  };

  // per-thread read addresses: row = (wrow|wcol)+mi*16+l15, chunk = lg^((l15>>1)&3)
  const unsigned chm = (unsigned)((lg ^ ((l15 >> 1) & 3)) * 16);
  const unsigned aAddr = lds_addr(lds) + (unsigned)((wrow + l15) * 64) + chm;
  const unsigned bAddr = lds_addr(lds) + 65536u + (unsigned)((wcol + l15) * 64) + chm;

  // prologue: 3 units -> (0,k0),(0,k1),(1,k0); guard (0,k0) landed everywhere
  STAGE1(0, 0);
  STAGE1(0, 1);
  STAGE1(1, 0);
  VMG(8);
  __builtin_amdgcn_s_barrier();

  const int NT = K >> 6;  // even, >= 4 for all our shapes
  bf16x8 aR[4], bR[4];

  for (int t2 = 0; t2 < NT; t2 += 2) {
    const bool s3 = (t2 + 2) < NT;
    const bool s7 = (t2 + 3) < NT;

    // ph1: tile t2, kh0  [buf 0]
    RDX(0);
    STAGE1(t2 + 1, 1);                 // (odd,k1), read at ph7 (lead 6 phases)
    BAR_LGKM(); MFQH(0);
    __builtin_amdgcn_s_barrier();
    // ph2
    RDY(0);
    BAR_LGKM(); MFQH(1);
    VMG(8);                            // guard ph3's (t2,k1) [staged prev ph5]
    __builtin_amdgcn_s_barrier();
    // ph3: tile t2, kh1  [buf 16384]
    RDX(16384);
    if (s3) STAGE1(t2 + 2, 0);
    BAR_LGKM(); MFQH(0);
    __builtin_amdgcn_s_barrier();
    // ph4
    RDY(16384);
    BAR_LGKM(); MFQH(1);
    if (s3) VMG(8); else VMG(4);       // guard ph5's (t2+1,k0) [prev ph7]
    __builtin_amdgcn_s_barrier();
    // ph5: tile t2+1, kh0  [buf 32768]
    RDX(32768);
    if (s3) STAGE1(t2 + 2, 1);
    BAR_LGKM(); MFQH(0);
    __builtin_amdgcn_s_barrier();
    // ph6
    RDY(32768);
    BAR_LGKM(); MFQH(1);
    if (s3) VMG(8); else VMG(0);       // guard ph7's (t2+1,k1) [cur ph1]
    __builtin_amdgcn_s_barrier();
    // ph7: tile t2+1, kh1  [buf 49152]
    RDX(49152);
    if (s7) STAGE1(t2 + 3, 0);
    BAR_LGKM(); MFQH(0);
    __builtin_amdgcn_s_barrier();
    // ph8
    RDY(49152);
    BAR_LGKM(); MFQH(1);
    if (s3) { if (s7) VMG(8); else VMG(4); }  // guard next ph1's (t2+2,k0) [cur ph3]
    __builtin_amdgcn_s_barrier();
  }

  // Epilogue. C/D frag: col = lane&15, row = (lane>>4)*4 + reg  [m89-verified]
  if constexpr (EPI == EPI_BF16_T) {
    // Coalesced C^T write via LDS restage (fixes 8x write amplification of
    // direct stride-batchM short4 stores). LDS free: after the loop's final
    // barrier every wave has completed its ds_reads (lgkm0 precedes MFMA).
    // LDS layout: local row n (0..255) at n*512B; 16B chunk q holds
    // m in [8q, 8q+8), chunk swizzled q ^= (n&7)<<2 (write ~2-way, read free).
    char* Tl = (char*)lds;
    const unsigned sN = (unsigned)((l15 & 7) << 2);
#pragma unroll
    for (int mi = 0; mi < 8; ++mi) {
      const int m0 = wrow + mi * 16 + lg * 4;
      const unsigned cm = (unsigned)(m0 >> 3);
      const unsigned off8 = (unsigned)((m0 & 7) * 2);
#pragma unroll
      for (int ni = 0; ni < 4; ++ni) {
        const int n = wcol + ni * 16 + l15;
        union { short4 s4; short h[4]; } u;
#pragma unroll
        for (int r = 0; r < 4; ++r) {
          bf16 bv = __float2bfloat16(acc[mi][ni][r]);
          u.h[r] = *(short*)&bv;
        }
        *(short4*)(Tl + n * 512 + (((cm ^ sN) << 4) + off8)) = u.s4;
      }
    }
    __syncthreads();
    bf16* C = (bf16*)Cv + (size_t)zb * (size_t)sCz;
    const int bi = brow / batchM;          // tile lies within one batch slice
    const int ms0 = brow - bi * batchM;
    const int q5 = t & 31;                 // 16B chunk within a row
    const int nr0 = t >> 5;                // 0..15
    const unsigned rs = (unsigned)((nr0 & 7) << 2);
    const unsigned rdoff = (((unsigned)q5 ^ rs) << 4);
    bf16* Cb = C + (size_t)bi * (size_t)N * (size_t)batchM + (size_t)ms0 + (size_t)q5 * 8;
#pragma unroll
    for (int p = 0; p < 16; ++p) {
      const int n = nr0 + p * 16;          // local row; n&7 == nr0&7
      bf16x8 v = *(const bf16x8*)(Tl + n * 512 + rdoff);
      *(bf16x8*)(Cb + (size_t)(bcol + n) * (size_t)batchM) = v;
    }
  } else {
#pragma unroll
    for (int mi = 0; mi < 8; ++mi) {
#pragma unroll
      for (int r = 0; r < 4; ++r) {
        const int m = brow + wrow + mi * 16 + lg * 4 + r;
#pragma unroll
        for (int ni = 0; ni < 4; ++ni) {
          const int n = bcol + wcol + ni * 16 + l15;
          const size_t idx = (size_t)m * (size_t)N + (size_t)n;
          float v = acc[mi][ni][r];
          if constexpr (EPI == EPI_F32_KSPLIT) {
            float* C = (part ? (float*)auxv : (float*)Cv) + (size_t)zb * (size_t)sCz;
            C[idx] = v;
          } else if constexpr (EPI == EPI_F32_RES) {
            ((float*)Cv)[idx] = v + ((const float*)auxv)[idx];
          } else if constexpr (EPI == EPI_BF16) {
            ((bf16*)Cv)[idx] = __float2bfloat16(v);
          } else if constexpr (EPI == EPI_BF16_GELU) {
            v = 0.5f * v * (1.0f + erff(v * 0.70710678118654752f));
            ((bf16*)Cv)[idx] = __float2bfloat16(v);
          } else if constexpr (EPI == EPI_BF16_MUL) {
            v = v * __bfloat162float(((const bf16*)auxv)[idx]);
            ((bf16*)Cv)[idx] = __float2bfloat16(v);
          }
        }
      }
    }
  }
}

// LayerNorm over rows of 2048 fp32 -> bf16 (biased var, eps=1e-5, weight, no bias)
__global__ __launch_bounds__(256) void ln_k(const float* __restrict__ x,
                                            const float* __restrict__ w,
                                            bf16* __restrict__ out) {
  const int row = blockIdx.x;
  const int t = threadIdx.x;
  const float* xr = x + (size_t)row * 2048;
  float4 a = ((const float4*)xr)[2 * t];
  float4 b = ((const float4*)xr)[2 * t + 1];
  float s = a.x + a.y + a.z + a.w + b.x + b.y + b.z + b.w;
  float ss = a.x * a.x + a.y * a.y + a.z * a.z + a.w * a.w +
             b.x * b.x + b.y * b.y + b.z * b.z + b.w * b.w;
#pragma unroll
  for (int o = 1; o < 64; o <<= 1) { s += __shfl_xor(s, o); ss += __shfl_xor(ss, o); }
  __shared__ float ps[4], pss[4];
  if ((t & 63) == 0) { ps[t >> 6] = s; pss[t >> 6] = ss; }
  __syncthreads();
  s = ps[0] + ps[1] + ps[2] + ps[3];
  ss = pss[0] + pss[1] + pss[2] + pss[3];
  const float mean = s * (1.0f / 2048.0f);
  const float var = ss * (1.0f / 2048.0f) - mean * mean;
  const float rstd = rsqrtf(var + 1e-5f);
  float4 wa = ((const float4*)w)[2 * t];
  float4 wb = ((const float4*)w)[2 * t + 1];
  bf16* o8 = out + (size_t)row * 2048 + (size_t)t * 8;
  o8[0] = __float2bfloat16((a.x - mean) * rstd * wa.x);
  o8[1] = __float2bfloat16((a.y - mean) * rstd * wa.y);
  o8[2] = __float2bfloat16((a.z - mean) * rstd * wa.z);
  o8[3] = __float2bfloat16((a.w - mean) * rstd * wa.w);
  o8[4] = __float2bfloat16((b.x - mean) * rstd * wb.x);
  o8[5] = __float2bfloat16((b.y - mean) * rstd * wb.y);
  o8[6] = __float2bfloat16((b.z - mean) * rstd * wb.z);
  o8[7] = __float2bfloat16((b.w - mean) * rstd * wb.w);
}

// softmax over rows of 2048: input = sp0 + sp1 (split-K partials), scale 1/8 -> bf16
__global__ __launch_bounds__(256) void softmax2_k(const float* __restrict__ s0,
                                                  const float* __restrict__ s1,
                                                  bf16* __restrict__ o) {
  const int row = blockIdx.x;
  const int t = threadIdx.x;
  const float* r0 = s0 + (size_t)row * 2048;
  const float* r1 = s1 + (size_t)row * 2048;
  float4 a = ((const float4*)r0)[2 * t];
  float4 b = ((const float4*)r0)[2 * t + 1];
  float4 c = ((const float4*)r1)[2 * t];
  float4 d = ((const float4*)r1)[2 * t + 1];
  float v[8] = {a.x + c.x, a.y + c.y, a.z + c.z, a.w + c.w,
                b.x + d.x, b.y + d.y, b.z + d.z, b.w + d.w};
  float m = -1e30f;
#pragma unroll
  for (int i = 0; i < 8; ++i) { v[i] *= 0.125f; m = fmaxf(m, v[i]); }
#pragma unroll
  for (int o2 = 1; o2 < 64; o2 <<= 1) m = fmaxf(m, __shfl_xor(m, o2));
  __shared__ float red[4];
  if ((t & 63) == 0) red[t >> 6] = m;
  __syncthreads();
  m = fmaxf(fmaxf(red[0], red[1]), fmaxf(red[2], red[3]));
  float sum = 0.f;
#pragma unroll
  for (int i = 0; i < 8; ++i) { v[i] = __expf(v[i] - m); sum += v[i]; }
#pragma unroll
  for (int o2 = 1; o2 < 64; o2 <<= 1) sum += __shfl_xor(sum, o2);
  __syncthreads();
  if ((t & 63) == 0) red[t >> 6] = sum;
  __syncthreads();
  sum = red[0] + red[1] + red[2] + red[3];
  const float inv = 1.0f / sum;
  bf16* po = o + (size_t)row * 2048 + (size_t)t * 8;
#pragma unroll
  for (int i = 0; i < 8; ++i) po[i] = __float2bfloat16(v[i] * inv);
}

// fp32 [K][N] -> bf16 [N][K]  (LDS-tiled transpose + downconvert)
__global__ __launch_bounds__(256) void transp_k(const float* __restrict__ in,
                                                bf16* __restrict__ out,
                                                int K, int N) {
  __shared__ float tile[32][33];
  const int bn = blockIdx.x * 32;
  const int bk = blockIdx.y * 32;
  const int tx = threadIdx.x;
  const int ty = threadIdx.y;
#pragma unroll
  for (int i = 0; i < 32; i += 8)
    tile[ty + i][tx] = in[(size_t)(bk + ty + i) * N + bn + tx];
  __syncthreads();
#pragma unroll
  for (int i = 0; i < 32; i += 8)
    out[(size_t)(bn + ty + i) * K + bk + tx] = __float2bfloat16(tile[tx][ty + i]);
}

extern "C" void kernel_launch(void* const* d_in, const int* in_sizes, int n_in,
                              void* d_out, int out_size, void* d_ws, size_t ws_size,
                              hipStream_t stream) {
  (void)in_sizes; (void)n_in; (void)out_size; (void)ws_size;
  const float* x   = (const float*)d_in[0];
  const float* lnw = (const float*)d_in[1];
  const float* w_q = (const float*)d_in[2];
  const float* w_k = (const float*)d_in[3];
  const float* w_v = (const float*)d_in[4];
  const float* w_o = (const float*)d_in[5];
  const float* w_g = (const float*)d_in[6];
  const float* w_u = (const float*)d_in[7];
  const float* w_d = (const float*)d_in[8];
  float* out = (float*)d_out;

  const int E = 2048, F = 8192;
  const size_t MB = 1024ull * 1024ull;
  char* ws = (char*)d_ws;

  // ---- workspace (288 MB, regions reused across phases) ----
  bf16* wq_t = (bf16*)(ws + 0 * MB);     // 8MB  [E][E] = w_q^T
  bf16* wk_t = (bf16*)(ws + 8 * MB);     // 8MB
  bf16* wv_t = (bf16*)(ws + 16 * MB);    // 8MB
  bf16* wo_t = (bf16*)(ws + 24 * MB);    // 8MB
  bf16* wg_t = (bf16*)(ws + 32 * MB);    // 32MB [F][E] = w_gate^T
  bf16* wu_t = (bf16*)(ws + 64 * MB);    // 32MB
  bf16* wd_t = (bf16*)(ws + 96 * MB);    // 32MB [E][F] = w_down^T
  bf16*  h   = (bf16*)(ws + 128 * MB);   // 32MB  h -> sp0 -> h2
  float* sp0 = (float*)(ws + 128 * MB);
  bf16*  h2  = (bf16*)(ws + 128 * MB);
  bf16*  qt    = (bf16*)(ws + 160 * MB); // 32MB  qt -> attnT -> gc(lo)
  bf16*  attnT = (bf16*)(ws + 160 * MB);
  bf16*  gc    = (bf16*)(ws + 160 * MB); // 64MB [160,224)
  bf16*  kt  = (bf16*)(ws + 192 * MB);   // 32MB  kt -> wts -> gc(hi)
  bf16*  wts = (bf16*)(ws + 192 * MB);
  bf16*  vm  = (bf16*)(ws + 224 * MB);   // 32MB  vm -> x2(lo)
  float* x2  = (float*)(ws + 224 * MB);  // 64MB [224,288)
  float* sp1 = (float*)(ws + 256 * MB);  // 32MB  (dead before x2 grows over it)

  dim3 blk(256), tb(32, 8), g512(512);

  transp_k<<<dim3(E / 32, E / 32), tb, 0, stream>>>(w_q, wq_t, E, E);
  transp_k<<<dim3(E / 32, E / 32), tb, 0, stream>>>(w_k, wk_t, E, E);
  transp_k<<<dim3(E / 32, E / 32), tb, 0, stream>>>(w_v, wv_t, E, E);
  transp_k<<<dim3(E / 32, E / 32), tb, 0, stream>>>(w_o, wo_t, E, E);
  transp_k<<<dim3(F / 32, E / 32), tb, 0, stream>>>(w_g, wg_t, E, F);
  transp_k<<<dim3(F / 32, E / 32), tb, 0, stream>>>(w_u, wu_t, E, F);
  transp_k<<<dim3(E / 32, F / 32), tb, 0, stream>>>(w_d, wd_t, F, E);

  ln_k<<<8192, blk, 0, stream>>>(x, lnw, h);

  // q,k written transposed per batch: qt[b][e][s]; v natural: vm[b*s][e']
  gemm256_k<EPI_BF16_T><<<dim3(8, 32, 1), g512, 0, stream>>>(h, wq_t, qt, nullptr,
      2048, 2048, 2048, 2048, 0, 0, 0, 4096);
  gemm256_k<EPI_BF16_T><<<dim3(8, 32, 1), g512, 0, stream>>>(h, wk_t, kt, nullptr,
      2048, 2048, 2048, 2048, 0, 0, 0, 4096);
  gemm256_k<EPI_BF16><<<dim3(8, 32, 1), g512, 0, stream>>>(h, wv_t, vm, nullptr,
      2048, 2048, 2048, 2048, 0, 0, 0, 1);

  // scores split-K: z = (part<<1)|batch; partial p sums s in [p*2048,(p+1)*2048)
  gemm256_k<EPI_F32_KSPLIT><<<dim3(8, 8, 4), g512, 0, stream>>>(qt, kt, sp0, sp1,
      2048, 2048, 4096, 4096, (long)2048 * 4096, (long)2048 * 4096,
      (long)2048 * 2048, 2048);

  softmax2_k<<<4096, blk, 0, stream>>>(sp0, sp1, wts);

  // attn[b][e][s] = wts[b] @ vm[b]^T -> stored transposed: attnT[b][s][e]
  gemm256_k<EPI_BF16_T><<<dim3(16, 8, 2), g512, 0, stream>>>(wts, vm, attnT, nullptr,
      4096, 2048, 2048, 2048, (long)2048 * 2048, (long)4096 * 2048,
      (long)4096 * 2048, 2048);

  // x2 = attnT @ w_o + x   (fp32)
  gemm256_k<EPI_F32_RES><<<dim3(8, 32, 1), g512, 0, stream>>>(attnT, wo_t, x2, x,
      2048, 2048, 2048, 2048, 0, 0, 0, 1);

  ln_k<<<8192, blk, 0, stream>>>(x2, lnw, h2);

  // FFN in 2 chunks of F/2=4096: gate->gelu, up*gate, down(+residual/accumulate)
  for (int c = 0; c < 2; ++c) {
    gemm256_k<EPI_BF16_GELU><<<dim3(16, 32, 1), g512, 0, stream>>>(
        h2, wg_t + (size_t)c * 4096 * 2048, gc, nullptr,
        4096, 2048, 2048, 2048, 0, 0, 0, 1);
    gemm256_k<EPI_BF16_MUL><<<dim3(16, 32, 1), g512, 0, stream>>>(
        h2, wu_t + (size_t)c * 4096 * 2048, gc, gc,
        4096, 2048, 2048, 2048, 0, 0, 0, 1);
    gemm256_k<EPI_F32_RES><<<dim3(8, 32, 1), g512, 0, stream>>>(
        gc, wd_t + (size_t)c * 4096, out,
        (c == 0 ? (const void*)x2 : (const void*)out),
        2048, 4096, 4096, 8192, 0, 0, 0, 1);
  }
}

// Round 9
// 1450.047 us; speedup vs baseline: 1.0772x; 1.0208x over previous
//
#include <hip/hip_runtime.h>
#include <hip/hip_bf16.h>

typedef __hip_bfloat16 bf16;
typedef __attribute__((ext_vector_type(8))) short bf16x8;
typedef __attribute__((ext_vector_type(4))) float f32x4;

#define EPI_BF16 1
#define EPI_F32_RES 3
#define EPI_BF16_GELU 4
#define EPI_BF16_MUL 5
#define EPI_F32_KSPLIT 6

__device__ __forceinline__ void gload_lds16(const bf16* g, char* l) {
  __builtin_amdgcn_global_load_lds(
      (const __attribute__((address_space(1))) unsigned int*)g,
      (__attribute__((address_space(3))) unsigned int*)l, 16, 0, 0);
}

__device__ __forceinline__ unsigned lds_addr(const void* p) {
  return (unsigned)(size_t)(const __attribute__((address_space(3))) char*)p;
}

template<int IMM>
__device__ __forceinline__ bf16x8 dsr(unsigned addr) {
  bf16x8 d;
  asm volatile("ds_read_b128 %0, %1 offset:%c2" : "=v"(d) : "v"(addr), "i"(IMM));
  return d;
}

#define SCHED0() __builtin_amdgcn_sched_barrier(0)
#define VMG(N)                                       \
  do {                                               \
    SCHED0();                                        \
    asm volatile("s_waitcnt vmcnt(" #N ")");         \
    SCHED0();                                        \
  } while (0)
#define BAR_LGKM()                                   \
  do {                                               \
    __builtin_amdgcn_s_barrier();                    \
    SCHED0();                                        \
    asm volatile("s_waitcnt lgkmcnt(0)");            \
    SCHED0();                                        \
  } while (0)

// phase reads: X = A mi0-3 + B nj0-3 (8 x b128), Y = A mi4-7 (4 x b128).
#define RDX(BUF)                                                            \
  do {                                                                      \
    aR[0] = dsr<(BUF) + 0>(aAddr);    aR[1] = dsr<(BUF) + 1024>(aAddr);     \
    aR[2] = dsr<(BUF) + 2048>(aAddr); aR[3] = dsr<(BUF) + 3072>(aAddr);     \
    bR[0] = dsr<(BUF) + 0>(bAddr);    bR[1] = dsr<(BUF) + 1024>(bAddr);     \
    bR[2] = dsr<(BUF) + 2048>(bAddr); bR[3] = dsr<(BUF) + 3072>(bAddr);     \
  } while (0)
#define RDY(BUF)                                                            \
  do {                                                                      \
    aR[0] = dsr<(BUF) + 4096>(aAddr); aR[1] = dsr<(BUF) + 5120>(aAddr);     \
    aR[2] = dsr<(BUF) + 6144>(aAddr); aR[3] = dsr<(BUF) + 7168>(aAddr);     \
  } while (0)

// 16 independent MFMAs (distinct accs; one K=32 half per phase), setprio (T5).
#define MFQH(MB)                                                            \
  do {                                                                      \
    __builtin_amdgcn_s_setprio(1);                                          \
    _Pragma("unroll") for (int mi_ = 0; mi_ < 4; ++mi_)                     \
        _Pragma("unroll") for (int nj_ = 0; nj_ < 4; ++nj_)                 \
            acc[(MB) * 4 + mi_][nj_] =                                      \
                __builtin_amdgcn_mfma_f32_16x16x32_bf16(                    \
                    aR[mi_], bR[nj_], acc[(MB) * 4 + mi_][nj_], 0, 0, 0);   \
    __builtin_amdgcn_s_setprio(0);                                          \
  } while (0)

// C = A(MxK,row-major,lda) * B^T, B stored [N x K] row-major (ldb).
// 256x256 tile, BK=64 split in two K-halves, 8 waves (2M x 4N).
// LDS 128KB as 4 sub-buffers/operand; 8 phases / 2 K-tiles; counted-vmcnt
// pipeline (R5 derivation). kOff = split-K offset (KSPLIT) in elements.
template<int EPI>
__global__ __launch_bounds__(512, 2) void gemm256_k(
    const bf16* __restrict__ A, const bf16* __restrict__ B,
    void* __restrict__ Cv, const void* __restrict__ auxv,
    int N, int K, int lda, int ldb,
    long sAz, long sBz, long sCz, int kOff)
{
  __shared__ bf16 lds[65536];  // 128KB: A units [0,64K), B units [64K,128K)

  // T1: XCD-aware swizzle over the flattened grid (all grids are %8==0)
  const int gx = gridDim.x, gy = gridDim.y;
  int lid = (blockIdx.z * gy + blockIdx.y) * gx + blockIdx.x;
  const int cpx = (gx * gy * gridDim.z) >> 3;
  lid = (lid & 7) * cpx + (lid >> 3);
  const int bx = lid % gx;
  const int rem = lid / gx;
  const int by = rem % gy;
  const int z = rem / gy;

  int zb = z, part = 0;
  if constexpr (EPI == EPI_F32_KSPLIT) { zb = z & 1; part = z >> 1; }
  A += (size_t)zb * (size_t)sAz + (size_t)part * (size_t)kOff;
  B += (size_t)zb * (size_t)sBz + (size_t)part * (size_t)kOff;

  const int brow = by * 256, bcol = bx * 256;
  const int t = threadIdx.x;
  const int w = t >> 6, lane = t & 63;
  const int wrow = (w >> 2) * 128;  // 2 M-waves
  const int wcol = (w & 3) * 64;    // 4 N-waves
  const int l15 = lane & 15, lg = lane >> 4;

  f32x4 acc[8][4];
#pragma unroll
  for (int i = 0; i < 8; ++i)
#pragma unroll
    for (int j = 0; j < 4; ++j) {
      f32x4 zz = {0.f, 0.f, 0.f, 0.f};
      acc[i][j] = zz;
    }

  // Stage one (tile,kh) unit: A 256x32 (16KB) + B 256x32, 4 gloads/thread.
  // chunk ^= (row>>1)&3; global source pre-swizzled (rule #21).
  auto STAGE1 = [&](int tile, int kh) {
    const int par = tile & 1;
    char* Ad = (char*)lds + (((par << 1) | kh) << 14);
    char* Bd = Ad + 65536;
    const int kk = tile * 64 + kh * 32;
    const int csw = (lane >> 3) & 3;
#pragma unroll
    for (int j = 0; j < 2; ++j) {
      const int bslot = (j * 8 + w) * 64;
      const int slot = bslot + lane;
      const int r = slot >> 2;
      const int cs = (slot & 3) ^ csw;
      gload_lds16(A + (size_t)(brow + r) * lda + kk + cs * 8, Ad + bslot * 16);
      gload_lds16(B + (size_t)(bcol + r) * ldb + kk + cs * 8, Bd + bslot * 16);
    }
  };

  const unsigned chm = (unsigned)((lg ^ ((l15 >> 1) & 3)) * 16);
  const unsigned aAddr = lds_addr(lds) + (unsigned)((wrow + l15) * 64) + chm;
  const unsigned bAddr = lds_addr(lds) + 65536u + (unsigned)((wcol + l15) * 64) + chm;

  STAGE1(0, 0);
  STAGE1(0, 1);
  STAGE1(1, 0);
  VMG(8);
  __builtin_amdgcn_s_barrier();

  const int NT = K >> 6;  // even, >= 4 for all our shapes
  bf16x8 aR[4], bR[4];

  for (int t2 = 0; t2 < NT; t2 += 2) {
    const bool s3 = (t2 + 2) < NT;
    const bool s7 = (t2 + 3) < NT;

    RDX(0);
    STAGE1(t2 + 1, 1);
    BAR_LGKM(); MFQH(0);
    __builtin_amdgcn_s_barrier();
    RDY(0);
    BAR_LGKM(); MFQH(1);
    VMG(8);
    __builtin_amdgcn_s_barrier();
    RDX(16384);
    if (s3) STAGE1(t2 + 2, 0);
    BAR_LGKM(); MFQH(0);
    __builtin_amdgcn_s_barrier();
    RDY(16384);
    BAR_LGKM(); MFQH(1);
    if (s3) VMG(8); else VMG(4);
    __builtin_amdgcn_s_barrier();
    RDX(32768);
    if (s3) STAGE1(t2 + 2, 1);
    BAR_LGKM(); MFQH(0);
    __builtin_amdgcn_s_barrier();
    RDY(32768);
    BAR_LGKM(); MFQH(1);
    if (s3) VMG(8); else VMG(0);
    __builtin_amdgcn_s_barrier();
    RDX(49152);
    if (s7) STAGE1(t2 + 3, 0);
    BAR_LGKM(); MFQH(0);
    __builtin_amdgcn_s_barrier();
    RDY(49152);
    BAR_LGKM(); MFQH(1);
    if (s3) { if (s7) VMG(8); else VMG(4); }
    __builtin_amdgcn_s_barrier();
  }

  // Epilogue. C/D frag: col = lane&15, row = (lane>>4)*4 + reg  [m89-verified]
#pragma unroll
  for (int mi = 0; mi < 8; ++mi) {
#pragma unroll
    for (int r = 0; r < 4; ++r) {
      const int m = brow + wrow + mi * 16 + lg * 4 + r;
#pragma unroll
      for (int ni = 0; ni < 4; ++ni) {
        const int n = bcol + wcol + ni * 16 + l15;
        const size_t idx = (size_t)m * (size_t)N + (size_t)n;
        float v = acc[mi][ni][r];
        if constexpr (EPI == EPI_F32_KSPLIT) {
          float* C = (part ? (float*)auxv : (float*)Cv) + (size_t)zb * (size_t)sCz;
          C[idx] = v;
        } else if constexpr (EPI == EPI_F32_RES) {
          float* C = (float*)Cv + (size_t)zb * (size_t)sCz;
          const float* ax = (const float*)auxv + (size_t)zb * (size_t)sCz;
          C[idx] = v + ax[idx];
        } else if constexpr (EPI == EPI_BF16) {
          ((bf16*)Cv)[idx] = __float2bfloat16(v);
        } else if constexpr (EPI == EPI_BF16_GELU) {
          v = 0.5f * v * (1.0f + erff(v * 0.70710678118654752f));
          ((bf16*)Cv)[idx] = __float2bfloat16(v);
        } else if constexpr (EPI == EPI_BF16_MUL) {
          v = v * __bfloat162float(((const bf16*)auxv)[idx]);
          ((bf16*)Cv)[idx] = __float2bfloat16(v);
        }
      }
    }
  }
}

// LayerNorm over rows of 2048 fp32 -> bf16 (biased var, eps=1e-5, weight, no bias)
__global__ __launch_bounds__(256) void ln_k(const float* __restrict__ x,
                                            const float* __restrict__ w,
                                            bf16* __restrict__ out) {
  const int row = blockIdx.x;
  const int t = threadIdx.x;
  const float* xr = x + (size_t)row * 2048;
  float4 a = ((const float4*)xr)[2 * t];
  float4 b = ((const float4*)xr)[2 * t + 1];
  float s = a.x + a.y + a.z + a.w + b.x + b.y + b.z + b.w;
  float ss = a.x * a.x + a.y * a.y + a.z * a.z + a.w * a.w +
             b.x * b.x + b.y * b.y + b.z * b.z + b.w * b.w;
#pragma unroll
  for (int o = 1; o < 64; o <<= 1) { s += __shfl_xor(s, o); ss += __shfl_xor(ss, o); }
  __shared__ float ps[4], pss[4];
  if ((t & 63) == 0) { ps[t >> 6] = s; pss[t >> 6] = ss; }
  __syncthreads();
  s = ps[0] + ps[1] + ps[2] + ps[3];
  ss = pss[0] + pss[1] + pss[2] + pss[3];
  const float mean = s * (1.0f / 2048.0f);
  const float var = ss * (1.0f / 2048.0f) - mean * mean;
  const float rstd = rsqrtf(var + 1e-5f);
  float4 wa = ((const float4*)w)[2 * t];
  float4 wb = ((const float4*)w)[2 * t + 1];
  bf16* o8 = out + (size_t)row * 2048 + (size_t)t * 8;
  o8[0] = __float2bfloat16((a.x - mean) * rstd * wa.x);
  o8[1] = __float2bfloat16((a.y - mean) * rstd * wa.y);
  o8[2] = __float2bfloat16((a.z - mean) * rstd * wa.z);
  o8[3] = __float2bfloat16((a.w - mean) * rstd * wa.w);
  o8[4] = __float2bfloat16((b.x - mean) * rstd * wb.x);
  o8[5] = __float2bfloat16((b.y - mean) * rstd * wb.y);
  o8[6] = __float2bfloat16((b.z - mean) * rstd * wb.z);
  o8[7] = __float2bfloat16((b.w - mean) * rstd * wb.w);
}

// softmax over rows of 2048: input = sp0 + sp1 (split-K partials), scale 1/8 -> bf16
__global__ __launch_bounds__(256) void softmax2_k(const float* __restrict__ s0,
                                                  const float* __restrict__ s1,
                                                  bf16* __restrict__ o) {
  const int row = blockIdx.x;
  const int t = threadIdx.x;
  const float* r0 = s0 + (size_t)row * 2048;
  const float* r1 = s1 + (size_t)row * 2048;
  float4 a = ((const float4*)r0)[2 * t];
  float4 b = ((const float4*)r0)[2 * t + 1];
  float4 c = ((const float4*)r1)[2 * t];
  float4 d = ((const float4*)r1)[2 * t + 1];
  float v[8] = {a.x + c.x, a.y + c.y, a.z + c.z, a.w + c.w,
                b.x + d.x, b.y + d.y, b.z + d.z, b.w + d.w};
  float m = -1e30f;
#pragma unroll
  for (int i = 0; i < 8; ++i) { v[i] *= 0.125f; m = fmaxf(m, v[i]); }
#pragma unroll
  for (int o2 = 1; o2 < 64; o2 <<= 1) m = fmaxf(m, __shfl_xor(m, o2));
  __shared__ float red[4];
  if ((t & 63) == 0) red[t >> 6] = m;
  __syncthreads();
  m = fmaxf(fmaxf(red[0], red[1]), fmaxf(red[2], red[3]));
  float sum = 0.f;
#pragma unroll
  for (int i = 0; i < 8; ++i) { v[i] = __expf(v[i] - m); sum += v[i]; }
#pragma unroll
  for (int o2 = 1; o2 < 64; o2 <<= 1) sum += __shfl_xor(sum, o2);
  __syncthreads();
  if ((t & 63) == 0) red[t >> 6] = sum;
  __syncthreads();
  sum = red[0] + red[1] + red[2] + red[3];
  const float inv = 1.0f / sum;
  bf16* po = o + (size_t)row * 2048 + (size_t)t * 8;
#pragma unroll
  for (int i = 0; i < 8; ++i) po[i] = __float2bfloat16(v[i] * inv);
}

// fp32 [K][N] -> bf16 [N][K]  (LDS-tiled transpose + downconvert)
__global__ __launch_bounds__(256) void transp_k(const float* __restrict__ in,
                                                bf16* __restrict__ out,
                                                int K, int N) {
  __shared__ float tile[32][33];
  const int bn = blockIdx.x * 32;
  const int bk = blockIdx.y * 32;
  const int tx = threadIdx.x;
  const int ty = threadIdx.y;
#pragma unroll
  for (int i = 0; i < 32; i += 8)
    tile[ty + i][tx] = in[(size_t)(bk + ty + i) * N + bn + tx];
  __syncthreads();
#pragma unroll
  for (int i = 0; i < 32; i += 8)
    out[(size_t)(bn + ty + i) * K + bk + tx] = __float2bfloat16(tile[tx][ty + i]);
}

// bf16 [R][C] -> bf16 [C][R], z-batched
__global__ __launch_bounds__(256) void transb_k(const bf16* __restrict__ in,
                                                bf16* __restrict__ out,
                                                int R, int C) {
  __shared__ bf16 tile[32][34];
  const size_t zo = (size_t)blockIdx.z * (size_t)R * (size_t)C;
  in += zo; out += zo;
  const int bc = blockIdx.x * 32;
  const int br = blockIdx.y * 32;
  const int tx = threadIdx.x;
  const int ty = threadIdx.y;
#pragma unroll
  for (int i = 0; i < 32; i += 8)
    tile[ty + i][tx] = in[(size_t)(br + ty + i) * C + bc + tx];
  __syncthreads();
#pragma unroll
  for (int i = 0; i < 32; i += 8)
    out[(size_t)(bc + ty + i) * R + br + tx] = tile[tx][ty + i];
}

// out_bf16[i] = bf16(a[i] + b[i]), n4 float4s (one elem4 per thread)
__global__ __launch_bounds__(256) void combine_k(const float* __restrict__ a,
                                                 const float* __restrict__ b,
                                                 bf16* __restrict__ o, int n4) {
  int i = blockIdx.x * 256 + threadIdx.x;
  if (i >= n4) return;
  float4 x = ((const float4*)a)[i];
  float4 y = ((const float4*)b)[i];
  bf16* po = o + (size_t)i * 4;
  po[0] = __float2bfloat16(x.x + y.x);
  po[1] = __float2bfloat16(x.y + y.y);
  po[2] = __float2bfloat16(x.z + y.z);
  po[3] = __float2bfloat16(x.w + y.w);
}

extern "C" void kernel_launch(void* const* d_in, const int* in_sizes, int n_in,
                              void* d_out, int out_size, void* d_ws, size_t ws_size,
                              hipStream_t stream) {
  (void)in_sizes; (void)n_in; (void)out_size; (void)ws_size;
  const float* x   = (const float*)d_in[0];
  const float* lnw = (const float*)d_in[1];
  const float* w_q = (const float*)d_in[2];
  const float* w_k = (const float*)d_in[3];
  const float* w_v = (const float*)d_in[4];
  const float* w_o = (const float*)d_in[5];
  const float* w_g = (const float*)d_in[6];
  const float* w_u = (const float*)d_in[7];
  const float* w_d = (const float*)d_in[8];
  float* out = (float*)d_out;

  const int E = 2048, F = 8192, S = 4096;
  const size_t MB = 1024ull * 1024ull;
  char* ws = (char*)d_ws;

  // ---- workspace (288 MB) ----
  bf16* wq_t = (bf16*)(ws + 0 * MB);     // 8MB  Wq^T
  bf16* wk_t = (bf16*)(ws + 8 * MB);     // 8MB
  bf16* wv_t = (bf16*)(ws + 16 * MB);    // 8MB
  bf16* wo_t = (bf16*)(ws + 24 * MB);    // 8MB
  bf16* wg_t = (bf16*)(ws + 32 * MB);    // 32MB
  bf16* wu_t = (bf16*)(ws + 64 * MB);    // 32MB
  bf16* wd_t = (bf16*)(ws + 96 * MB);    // 32MB
  bf16*  h    = (bf16*)(ws + 128 * MB);  // 32MB  h -> h2 (h dead after hT,v)
  bf16*  h2   = (bf16*)(ws + 128 * MB);
  bf16*  hT   = (bf16*)(ws + 160 * MB);  // 32MB [2][E][S]; dead after G
  bf16*  Gb   = (bf16*)(ws + 160 * MB);  // 16MB [2][E][E]  (over hT lo)
  bf16*  wts  = (bf16*)(ws + 160 * MB);  //      (over Gb after T1/T2 done)
  bf16*  T1b  = (bf16*)(ws + 176 * MB);  // 16MB (over hT hi)
  bf16*  wtsT = (bf16*)(ws + 176 * MB);  //      (over T1b after T2)
  bf16*  UT   = (bf16*)(ws + 176 * MB);  //      (over wtsT after UT-gemm)
  bf16*  gc   = (bf16*)(ws + 160 * MB);  // 64MB FFN chunk (all above dead)
  bf16*  vm   = (bf16*)(ws + 192 * MB);  // 32MB [2][S][E]; dead after x2
  float* p0   = (float*)(ws + 224 * MB); // 32MB fp32 partials [2][E][E]
  float* p1   = (float*)(ws + 256 * MB); // 32MB
  float* x2   = (float*)(ws + 224 * MB); // 64MB (over p0/p1 after UT)

  dim3 blk(256), tb(32, 8), g512(512);
  const long EE = (long)E * E;

  // weights -> bf16 transposed
  transp_k<<<dim3(E / 32, E / 32), tb, 0, stream>>>(w_q, wq_t, E, E);
  transp_k<<<dim3(E / 32, E / 32), tb, 0, stream>>>(w_k, wk_t, E, E);
  transp_k<<<dim3(E / 32, E / 32), tb, 0, stream>>>(w_v, wv_t, E, E);
  transp_k<<<dim3(E / 32, E / 32), tb, 0, stream>>>(w_o, wo_t, E, E);
  transp_k<<<dim3(F / 32, E / 32), tb, 0, stream>>>(w_g, wg_t, E, F);
  transp_k<<<dim3(F / 32, E / 32), tb, 0, stream>>>(w_u, wu_t, E, F);
  transp_k<<<dim3(E / 32, F / 32), tb, 0, stream>>>(w_d, wd_t, F, E);

  ln_k<<<8192, blk, 0, stream>>>(x, lnw, h);

  // hT[b][e][s] = h[b][s][e]
  transb_k<<<dim3(E / 32, S / 32, 2), tb, 0, stream>>>(h, hT, S, E);

  // v = h @ Wv  (natural layout vm[b*s][e])
  gemm256_k<EPI_BF16><<<dim3(8, 32, 1), g512, 0, stream>>>(h, wv_t, vm, nullptr,
      E, E, E, E, 0, 0, 0, 0);

  // G[b] = hT[b] @ hT[b]^T = h^T h   (K=4096, split 2)
  gemm256_k<EPI_F32_KSPLIT><<<dim3(8, 8, 4), g512, 0, stream>>>(hT, hT, p0, p1,
      E, 2048, S, S, (long)E * S, (long)E * S, EE, 2048);
  combine_k<<<dim3(2 * E * E / 1024), blk, 0, stream>>>(p0, p1, Gb, 2 * E * E / 4);

  // T1[b] = Wq^T @ G[b]   (G symmetric => G used as B directly; K=2048 split 2)
  gemm256_k<EPI_F32_KSPLIT><<<dim3(8, 8, 4), g512, 0, stream>>>(wq_t, Gb, p0, p1,
      E, 1024, E, E, 0, EE, EE, 1024);
  combine_k<<<dim3(2 * E * E / 1024), blk, 0, stream>>>(p0, p1, T1b, 2 * E * E / 4);

  // scores[b] = T1[b] @ Wk  (B = Wk^T = wk_t; K=2048 split 2) -> softmax
  gemm256_k<EPI_F32_KSPLIT><<<dim3(8, 8, 4), g512, 0, stream>>>(T1b, wk_t, p0, p1,
      E, 1024, E, E, EE, 0, EE, 1024);
  softmax2_k<<<4096, blk, 0, stream>>>(p0, p1, wts);

  // wtsT[b] = wts[b]^T
  transb_k<<<dim3(E / 32, E / 32, 2), tb, 0, stream>>>(wts, wtsT, E, E);

  // U^T[b] = Wo^T @ wts[b]^T  ( = (weights^T Wo)^T ; K=2048 split 2)
  gemm256_k<EPI_F32_KSPLIT><<<dim3(8, 8, 4), g512, 0, stream>>>(wo_t, wtsT, p0, p1,
      E, 1024, E, E, 0, EE, EE, 1024);
  combine_k<<<dim3(2 * E * E / 1024), blk, 0, stream>>>(p0, p1, UT, 2 * E * E / 4);

  // x2[b] = vm[b] @ U[b] + x[b]   (B = U^T; per-batch z)
  gemm256_k<EPI_F32_RES><<<dim3(8, 16, 2), g512, 0, stream>>>(vm, UT, x2, x,
      E, E, E, E, (long)S * E, EE, (long)S * E, 0);

  ln_k<<<8192, blk, 0, stream>>>(x2, lnw, h2);

  // FFN in 2 chunks of F/2=4096
  for (int c = 0; c < 2; ++c) {
    gemm256_k<EPI_BF16_GELU><<<dim3(16, 32, 1), g512, 0, stream>>>(
        h2, wg_t + (size_t)c * 4096 * 2048, gc, nullptr,
        4096, E, E, E, 0, 0, 0, 0);
    gemm256_k<EPI_BF16_MUL><<<dim3(16, 32, 1), g512, 0, stream>>>(
        h2, wu_t + (size_t)c * 4096 * 2048, gc, gc,
        4096, E, E, E, 0, 0, 0, 0);
    gemm256_k<EPI_F32_RES><<<dim3(8, 32, 1), g512, 0, stream>>>(
        gc, wd_t + (size_t)c * 4096, out,
        (c == 0 ? (const void*)x2 : (const void*)out),
        E, 4096, 4096, F, 0, 0, 0, 0);
  }
}